// Round 3
// baseline (443.558 us; speedup 1.0000x reference)
//
#include <hip/hip_runtime.h>

namespace {
constexpr int D = 4096;   // d_model
constexpr int E = 64;     // n_experts
constexpr int M = 16384;  // B*S
constexpr int BM = 64;    // rows per block
constexpr int BK = 64;    // k per round
constexpr int NT = D / BK;      // 64 rounds
constexpr int NBLK = M / BM;    // 256 blocks

// output layout (floats, concatenated in reference return order)
constexpr int OFF_IDX = 0;         // [M][2]
constexpr int OFF_SCORES = 32768;  // [M][2]
constexpr int OFF_PROBS = 65536;   // [M][64]
constexpr int OFF_Z = 1114112;     // scalar
constexpr int OFF_IMP = 1114113;   // [64]
constexpr int OFF_LOAD = 1114177;  // [64]

constexpr int WS_STRIDE = 132;  // per-block stats: 64 imp | 64 cnt | 1 z2
}  // namespace

// global->LDS direct DMA, 16 B per lane (dest = wave-uniform base + lane*16)
__device__ __forceinline__ void gload16(const float* g, float* l) {
  __builtin_amdgcn_global_load_lds(
      (const __attribute__((address_space(1))) void*)g,
      (__attribute__((address_space(3))) void*)l, 16, 0, 0);
}

// ---------------------------------------------------------------------------
// Fused router. 256 blocks x 512 threads (8 waves = 8 wave-aligned k-slices,
// 8 k each per round). LDS 64 KB double-buffered (-> 2 blocks/CU, 4 waves/
// SIMD for pipe overlap), granule-major:
//   granule = 16B = (row, kc*4..kc*4+3), kc in [0,16);
//   slot(row,kc) = row*16 + (kc ^ (row>>3))
// Staging via global_load_lds with linear LDS dest; the swizzle is applied by
// permuting each lane's GLOBAL source address. Inner-loop ds_read_b128 per
// granule: 8 distinct bank-quads across ty/tx -> conflict-free, 8-way
// broadcast. 8x8 register tile; no staging VGPRs, no ds_writes.
// ---------------------------------------------------------------------------
__global__ __launch_bounds__(512, 2) void router_fused(
    const float* __restrict__ xg, const float* __restrict__ wg,
    float* __restrict__ out, float* __restrict__ ws) {
  __shared__ float smem[16384];  // 2 buffers x (X 4096 | W 4096 floats)

  const int t = threadIdx.x;
  const int u = t & 63;   // lane
  const int s = t >> 6;   // wave id = k-slice 0..7
  const int tx = u & 7;   // expert group (8 experts)
  const int ty = u >> 3;  // row group (8 rows)
  const int r0 = blockIdx.x * BM;

  // ---- staging roles: waves 0-3 stage X, waves 4-7 stage W ----
  // wave sw covers slots [sw*256, sw*256+256), 4 calls x 64 granules.
  // call c, lane u -> slot = sw*256 + c*64 + u:
  //   row = sw*16 + c*4 + (u>>4), kc = (u&15) ^ (row>>3),
  //   row>>3 = sw*2 + (c>>1)
  const int sw = s & 3;
  const float* gbase = (s < 4) ? (xg + (size_t)r0 * D) : wg;
  const int rA = sw * 16 + (u >> 4);  // rows for calls 0,1 (c=1 adds 4 rows)
  const int tyA = sw * 2;
  const float* srcA = gbase + (size_t)rA * D + (((u & 15) ^ tyA) << 2);
  const float* srcB =
      gbase + (size_t)(rA + 8) * D + (((u & 15) ^ (tyA + 1)) << 2);
  const int dstoff = (s < 4 ? 0 : 4096) + sw * 1024;  // floats

  auto stage = [&](int r, float* buf) {
    const int rk = r * BK;  // k advance (floats) within each row
    float* dst = buf + dstoff;
    gload16(srcA + rk, dst);
    gload16(srcA + rk + (size_t)4 * D, dst + 256);
    gload16(srcB + rk, dst + 512);
    gload16(srcB + rk + (size_t)4 * D, dst + 768);
  };

  // ---- read offsets (floats): granule (row,kc) at row*64 + (kc^(row>>3))*4
  // this slice's granule columns: kc = s*2 + kr, kr in {0,1}
  int xoff[2], woff[2];
#pragma unroll
  for (int kr = 0; kr < 2; ++kr) {
    const int kc = s * 2 + kr;
    xoff[kr] = ty * 512 + ((kc ^ ty) << 2);
    woff[kr] = 4096 + tx * 512 + ((kc ^ tx) << 2);
  }

  float acc[8][8];
#pragma unroll
  for (int i = 0; i < 8; ++i)
#pragma unroll
    for (int j = 0; j < 8; ++j) acc[i][j] = 0.f;

  stage(0, smem);  // buffer 0

  for (int r = 0; r < NT; ++r) {
    __syncthreads();  // tile r staged (compiler drains vmcnt before barrier)
    if (r + 1 < NT) stage(r + 1, smem + ((r + 1) & 1) * 8192);

    const float* buf = smem + (r & 1) * 8192;
#pragma unroll
    for (int kr = 0; kr < 2; ++kr) {
      float4 bw[8];
#pragma unroll
      for (int j = 0; j < 8; ++j)
        bw[j] = *(const float4*)&buf[woff[kr] + j * 64];
#pragma unroll
      for (int i = 0; i < 8; ++i) {
        const float4 ax = *(const float4*)&buf[xoff[kr] + i * 64];
#pragma unroll
        for (int j = 0; j < 8; ++j) {
          acc[i][j] = fmaf(ax.x, bw[j].x, acc[i][j]);
          acc[i][j] = fmaf(ax.y, bw[j].y, acc[i][j]);
          acc[i][j] = fmaf(ax.z, bw[j].z, acc[i][j]);
          acc[i][j] = fmaf(ax.w, bw[j].w, acc[i][j]);
        }
      }
    }
  }

  // ---- cross-slice reduction, distributed, in two 16-plane phases ----
  // plane p = i*4+jj holds acc[i][2jj..2jj+1] at index (s*64+u)*2.
  // Reader thread (s,u) owns row (u>>3)*8 + s -> needs planes (s%4)*4+qq in
  // phase (s>=4). 16 planes x 1024 floats = 16384 floats = full smem.
  float v[8];
#pragma unroll
  for (int q = 0; q < 8; ++q) v[q] = 0.f;

#pragma unroll
  for (int ph = 0; ph < 2; ++ph) {
    __syncthreads();  // buffers / previous phase dead
    {
      float* P = smem;
      const int su2 = (s * 64 + u) * 2;
#pragma unroll
      for (int ii = 0; ii < 4; ++ii)
#pragma unroll
        for (int jj = 0; jj < 4; ++jj)
          *(float2*)&P[(ii * 4 + jj) * 1024 + su2] =
              make_float2(acc[ph * 4 + ii][2 * jj],
                          acc[ph * 4 + ii][2 * jj + 1]);
    }
    __syncthreads();
    if ((s >> 2) == ph) {
      const float* P = smem;
      const int base_p = (s & 3) * 4;
#pragma unroll
      for (int sl = 0; sl < 8; ++sl)
#pragma unroll
        for (int qq = 0; qq < 4; ++qq) {
          const float2 f =
              *(const float2*)&P[(base_p + qq) * 1024 + (sl * 64 + u) * 2];
          v[2 * qq] += f.x;
          v[2 * qq + 1] += f.y;
        }
    }
  }

  const int row = (u >> 3) * 8 + s;
  const int ebase = (u & 7) * 8;
  const int gr = r0 + row;

  __syncthreads();  // P dead; stats region reusable
  float* PW = smem;                // [8][64] per-wave importance partials
  float* zw = smem + 512;          // [8] per-wave z2 partials
  int* cnt = (int*)(smem + 520);   // [64]
  if (t < 64) cnt[t] = 0;
  __syncthreads();

  // ---- per-row top-2 (lax.top_k ties: lower index wins) over 8 lanes ----
  float v1 = v[0]; int i1 = ebase;
  float v2 = -3.402823466e+38f; int i2 = 0;
#pragma unroll
  for (int q = 1; q < 8; ++q) {
    const float x = v[q];
    if (x > v1) { v2 = v1; i2 = i1; v1 = x; i1 = ebase + q; }
    else if (x > v2) { v2 = x; i2 = ebase + q; }
  }
#pragma unroll
  for (int m = 1; m <= 4; m <<= 1) {
    const float o1 = __shfl_xor(v1, m);
    const int oi1 = __shfl_xor(i1, m);
    const float o2 = __shfl_xor(v2, m);
    const int oi2 = __shfl_xor(i2, m);
    if (o1 > v1 || (o1 == v1 && oi1 < i1)) {
      const bool c2 = (o2 > v1) || (o2 == v1 && oi2 < i1);
      v2 = c2 ? o2 : v1; i2 = c2 ? oi2 : i1;
      v1 = o1; i1 = oi1;
    } else if (o1 > v2 || (o1 == v2 && oi1 < i2)) {
      v2 = o1; i2 = oi1;
    }
  }

  // ---- row softmax / z, fully in-register ----
  float p[8];
  float ssum = 0.f;
#pragma unroll
  for (int q = 0; q < 8; ++q) { p[q] = __expf(v[q] - v1); ssum += p[q]; }
#pragma unroll
  for (int m = 1; m <= 4; m <<= 1) ssum += __shfl_xor(ssum, m);
  const float rs = 1.f / ssum;
#pragma unroll
  for (int q = 0; q < 8; ++q) p[q] *= rs;

  {
    const float4 o0 = {p[0], p[1], p[2], p[3]};
    const float4 o1 = {p[4], p[5], p[6], p[7]};
    *(float4*)&out[OFF_PROBS + (size_t)gr * 64 + ebase] = o0;
    *(float4*)&out[OFF_PROBS + (size_t)gr * 64 + ebase + 4] = o1;
  }
  const float z = v1 + __logf(ssum);
  const float z2 = z * z;

  if ((u & 7) == 0) {  // one writer per row
    out[OFF_IDX + 2 * gr] = (float)i1;
    out[OFF_IDX + 2 * gr + 1] = (float)i2;
    const float e1 = __expf(v2 - v1);  // v2 <= v1, stable
    const float s0 = 1.f / (1.f + e1);
    out[OFF_SCORES + 2 * gr] = s0;
    out[OFF_SCORES + 2 * gr + 1] = e1 * s0;
    atomicAdd(&cnt[i1], 1);
    atomicAdd(&cnt[i2], 1);
  }

  // ---- per-wave stats: butterfly over lane bits 3..5 (the 8 row groups) ----
  float cs[8];
#pragma unroll
  for (int q = 0; q < 8; ++q) cs[q] = p[q];
#pragma unroll
  for (int m = 8; m <= 32; m <<= 1)
#pragma unroll
    for (int q = 0; q < 8; ++q) cs[q] += __shfl_xor(cs[q], m);
  float zs = z2;
#pragma unroll
  for (int m = 8; m <= 32; m <<= 1) zs += __shfl_xor(zs, m);
  if (u < 8) {
    const float4 c0 = {cs[0], cs[1], cs[2], cs[3]};
    const float4 c1 = {cs[4], cs[5], cs[6], cs[7]};
    *(float4*)&PW[s * 64 + u * 8] = c0;
    *(float4*)&PW[s * 64 + u * 8 + 4] = c1;
    if (u == 0) zw[s] = zs;
  }
  __syncthreads();

  // per-block stats -> ws (no global atomics; tiny reduce kernel finishes)
  if (t < 64) {
    float ic = 0.f;
#pragma unroll
    for (int w = 0; w < 8; ++w) ic += PW[w * 64 + t];
    ws[(size_t)blockIdx.x * WS_STRIDE + t] = ic;
    ws[(size_t)blockIdx.x * WS_STRIDE + 64 + t] = (float)cnt[t];
  } else if (t == 64) {
    float zz = 0.f;
#pragma unroll
    for (int w = 0; w < 8; ++w) zz += zw[w];
    ws[(size_t)blockIdx.x * WS_STRIDE + 128] = zz;
  }
}

// ---------------------------------------------------------------------------
// Final reduction over 256 per-block stat slots; 512 threads, 4-way k-split.
// ---------------------------------------------------------------------------
__global__ __launch_bounds__(512) void router_reduce(
    const float* __restrict__ ws, float* __restrict__ out) {
  __shared__ float part[4][128];
  __shared__ float zp[4];
  const int t = threadIdx.x;
  const int c = t >> 7;      // block-quarter 0..3
  const int slot = t & 127;  // 0..127 (64 imp | 64 cnt)
  float v = 0.f;
#pragma unroll 8
  for (int i = 0; i < 64; ++i)
    v += ws[(size_t)(c * 64 + i) * WS_STRIDE + slot];
  part[c][slot] = v;
  if (t < 4) {
    float zz = 0.f;
#pragma unroll 8
    for (int i = 0; i < 64; ++i)
      zz += ws[(size_t)(t * 64 + i) * WS_STRIDE + 128];
    zp[t] = zz;
  }
  __syncthreads();
  if (t < 128) {
    const float s4 = part[0][t] + part[1][t] + part[2][t] + part[3][t];
    if (t < 64)
      out[OFF_IMP + t] = s4 * (1.f / 16384.f);
    else
      // counts are integers; /32768 exact; denominator max(sum,1)=32768
      out[OFF_LOAD + (t - 64)] = s4 * (1.f / 32768.f);
  } else if (t == 128) {
    out[OFF_Z] = (zp[0] + zp[1] + zp[2] + zp[3]) * (1.f / 16384.f);
  }
}

extern "C" void kernel_launch(void* const* d_in, const int* in_sizes, int n_in,
                              void* d_out, int out_size, void* d_ws, size_t ws_size,
                              hipStream_t stream) {
  const float* x = (const float*)d_in[0];
  const float* wgate = (const float*)d_in[1];
  float* out = (float*)d_out;
  float* ws = (float*)d_ws;  // 256*132 floats, fully written each call

  router_fused<<<dim3(NBLK), dim3(512), 0, stream>>>(x, wgate, out, ws);
  router_reduce<<<dim3(1), dim3(512), 0, stream>>>(ws, out);
}

// Round 4
// 412.764 us; speedup vs baseline: 1.0746x; 1.0746x over previous
//
#include <hip/hip_runtime.h>

namespace {
constexpr int D = 4096;   // d_model
constexpr int E = 64;     // n_experts
constexpr int M = 16384;  // B*S
constexpr int BM = 32;    // rows per block
constexpr int BK = 64;    // k per round
constexpr int NT = D / BK;      // 64 rounds
constexpr int NBLK = M / BM;    // 512 blocks -> 2 blocks/CU

// output layout (floats, concatenated in reference return order)
constexpr int OFF_IDX = 0;         // [M][2]
constexpr int OFF_SCORES = 32768;  // [M][2]
constexpr int OFF_PROBS = 65536;   // [M][64]
constexpr int OFF_Z = 1114112;     // scalar
constexpr int OFF_IMP = 1114113;   // [64]
constexpr int OFF_LOAD = 1114177;  // [64]

constexpr int WS_STRIDE = 132;  // per-block stats: 64 imp | 64 cnt | 1 z2
}  // namespace

// global->LDS direct DMA, 16 B per lane (dest = wave-uniform base + lane*16)
__device__ __forceinline__ void gload16(const float* g, float* l) {
  __builtin_amdgcn_global_load_lds(
      (const __attribute__((address_space(1))) void*)g,
      (__attribute__((address_space(3))) void*)l, 16, 0, 0);
}

// ---------------------------------------------------------------------------
// Fused router. 512 blocks x 512 threads (8 waves = 8 k-slices, 8 k each per
// round). BM=32 -> 2 blocks/CU (4 waves/SIMD) so one block's barrier drain
// overlaps the other's compute. LDS 48 KB double-buffered, granule-major:
//   granule = 16B = (row, kc*4..kc*4+3), kc in [0,16)
//   X slot(row,kc) = row*16 + (kc ^ (row>>2)), rows 0..31   [floats 0..2048)
//   W slot(row,kc) = row*16 + (kc ^ (row>>3)), rows 0..63   [floats 2048..6144)
// Staging via global_load_lds, linear LDS dest, swizzle applied on the GLOBAL
// source address (3 calls/wave/round). Inner-loop ds_read_b128 per granule:
// 8 distinct bank-quads x 8-way broadcast -> conflict-free. acc[4][8]/thread.
// ---------------------------------------------------------------------------
__global__ __launch_bounds__(512, 4) void router_fused(
    const float* __restrict__ xg, const float* __restrict__ wg,
    float* __restrict__ out, float* __restrict__ ws) {
  __shared__ float smem[12288];  // 2 buffers x (X 2048 | W 4096 floats)

  const int t = threadIdx.x;
  const int u = t & 63;   // lane
  const int s = t >> 6;   // wave id = k-slice 0..7
  const int tx = u & 7;   // expert group (8 experts)
  const int ty = u >> 3;  // row group (4 rows)
  const int r0 = blockIdx.x * BM;

  // ---- staging: 24 DMA calls/round, wave s takes calls 3s..3s+2 ----
  // call c covers LDS floats [c*256, c*256+256) = slots c*64 + u.
  //  c<8  -> X: row = c*4 + (u>>4),      src kc = (u&15) ^ c        (row>>2==c)
  //  c>=8 -> W: row = (c-8)*4 + (u>>4),  src kc = (u&15) ^ ((c-8)>>1)
  const float* srcp[3];
  int dstf[3];
#pragma unroll
  for (int j = 0; j < 3; ++j) {
    const int c = 3 * s + j;
    dstf[j] = c * 256;
    if (c < 8) {
      const int row = c * 4 + (u >> 4);
      srcp[j] = xg + (size_t)(r0 + row) * D + (((u & 15) ^ c) << 2);
    } else {
      const int row = (c - 8) * 4 + (u >> 4);
      srcp[j] = wg + (size_t)row * D + (((u & 15) ^ ((c - 8) >> 1)) << 2);
    }
  }
  auto stage = [&](int r, float* buf) {
    const int rk = r * BK;
#pragma unroll
    for (int j = 0; j < 3; ++j) gload16(srcp[j] + rk, buf + dstf[j]);
  };

  // ---- read offsets (floats); this slice's granule cols kc = s*2 + kr ----
  // X granule (ty*4+i, kc) at (ty*4+i)*64 + ((kc^ty)<<2)      (row>>2==ty)
  // W granule (tx*8+j, kc) at 2048 + (tx*8+j)*64 + ((kc^tx)<<2)
  int xoff[2], woff[2];
#pragma unroll
  for (int kr = 0; kr < 2; ++kr) {
    const int kc = s * 2 + kr;
    xoff[kr] = ty * 256 + ((kc ^ ty) << 2);
    woff[kr] = 2048 + tx * 512 + ((kc ^ tx) << 2);
  }

  float acc[4][8];
#pragma unroll
  for (int i = 0; i < 4; ++i)
#pragma unroll
    for (int j = 0; j < 8; ++j) acc[i][j] = 0.f;

  stage(0, smem);  // buffer 0

  for (int r = 0; r < NT; ++r) {
    __syncthreads();  // tile r staged (compiler drains vmcnt before barrier)
    if (r + 1 < NT) stage(r + 1, smem + ((r + 1) & 1) * 6144);

    const float* buf = smem + (r & 1) * 6144;
#pragma unroll
    for (int kr = 0; kr < 2; ++kr) {
      float4 bw[8];
#pragma unroll
      for (int j = 0; j < 8; ++j)
        bw[j] = *(const float4*)&buf[woff[kr] + j * 64];
#pragma unroll
      for (int i = 0; i < 4; ++i) {
        const float4 ax = *(const float4*)&buf[xoff[kr] + i * 64];
#pragma unroll
        for (int j = 0; j < 8; ++j) {
          acc[i][j] = fmaf(ax.x, bw[j].x, acc[i][j]);
          acc[i][j] = fmaf(ax.y, bw[j].y, acc[i][j]);
          acc[i][j] = fmaf(ax.z, bw[j].z, acc[i][j]);
          acc[i][j] = fmaf(ax.w, bw[j].w, acc[i][j]);
        }
      }
    }
  }

  // ---- cross-slice reduction, two 8-plane phases (8192 floats each) ----
  // Writer (s,u) holds logits(row=ty*4+i, e=tx*8+j) in acc[i][j].
  // Plane (il,jj), il=i-2ph: float2 at (s*64+u)*2.
  // Reader (s<4,u) owns row (u>>3)*4+s, experts (u&7)*8.. -> planes i=s,
  // jj=qq at index (sl*64+u)*2; participates in phase ph = s>>1.
  float v[8];
#pragma unroll
  for (int q = 0; q < 8; ++q) v[q] = 0.f;

#pragma unroll
  for (int ph = 0; ph < 2; ++ph) {
    __syncthreads();  // gemm buffers / previous phase dead
    {
      float* P = smem;
      const int su2 = (s * 64 + u) * 2;
#pragma unroll
      for (int il = 0; il < 2; ++il)
#pragma unroll
        for (int jj = 0; jj < 4; ++jj)
          *(float2*)&P[(il * 4 + jj) * 1024 + su2] =
              make_float2(acc[ph * 2 + il][2 * jj],
                          acc[ph * 2 + il][2 * jj + 1]);
    }
    __syncthreads();
    if (s < 4 && (s >> 1) == ph) {
      const float* P = smem;
      const int base_p = (s & 1) * 4;
#pragma unroll
      for (int sl = 0; sl < 8; ++sl)
#pragma unroll
        for (int qq = 0; qq < 4; ++qq) {
          const float2 f =
              *(const float2*)&P[(base_p + qq) * 1024 + (sl * 64 + u) * 2];
          v[2 * qq] += f.x;
          v[2 * qq + 1] += f.y;
        }
    }
  }

  const int row = (u >> 3) * 4 + s;  // valid for s<4
  const int ebase = (u & 7) * 8;
  const int gr = r0 + row;

  __syncthreads();  // P dead; stats region reusable
  float* PW = smem;                // [4][64] per-wave importance partials
  float* zw = smem + 256;          // [4] per-wave z2 partials
  int* cnt = (int*)(smem + 260);   // [64]
  if (t < 64) cnt[t] = 0;
  __syncthreads();

  if (s < 4) {
    // ---- per-row top-2 (lax.top_k ties: lower index wins) over 8 lanes ----
    float v1 = v[0]; int i1 = ebase;
    float v2 = -3.402823466e+38f; int i2 = 0;
#pragma unroll
    for (int q = 1; q < 8; ++q) {
      const float x = v[q];
      if (x > v1) { v2 = v1; i2 = i1; v1 = x; i1 = ebase + q; }
      else if (x > v2) { v2 = x; i2 = ebase + q; }
    }
#pragma unroll
    for (int m = 1; m <= 4; m <<= 1) {
      const float o1 = __shfl_xor(v1, m);
      const int oi1 = __shfl_xor(i1, m);
      const float o2 = __shfl_xor(v2, m);
      const int oi2 = __shfl_xor(i2, m);
      if (o1 > v1 || (o1 == v1 && oi1 < i1)) {
        const bool c2 = (o2 > v1) || (o2 == v1 && oi2 < i1);
        v2 = c2 ? o2 : v1; i2 = c2 ? oi2 : i1;
        v1 = o1; i1 = oi1;
      } else if (o1 > v2 || (o1 == v2 && oi1 < i2)) {
        v2 = o1; i2 = oi1;
      }
    }

    // ---- row softmax / z, fully in-register ----
    float p[8];
    float ssum = 0.f;
#pragma unroll
    for (int q = 0; q < 8; ++q) { p[q] = __expf(v[q] - v1); ssum += p[q]; }
#pragma unroll
    for (int m = 1; m <= 4; m <<= 1) ssum += __shfl_xor(ssum, m);
    const float rs = 1.f / ssum;
#pragma unroll
    for (int q = 0; q < 8; ++q) p[q] *= rs;

    {
      const float4 o0 = {p[0], p[1], p[2], p[3]};
      const float4 o1 = {p[4], p[5], p[6], p[7]};
      *(float4*)&out[OFF_PROBS + (size_t)gr * 64 + ebase] = o0;
      *(float4*)&out[OFF_PROBS + (size_t)gr * 64 + ebase + 4] = o1;
    }
    const float z = v1 + __logf(ssum);
    const float z2 = z * z;

    if ((u & 7) == 0) {  // one writer per row
      out[OFF_IDX + 2 * gr] = (float)i1;
      out[OFF_IDX + 2 * gr + 1] = (float)i2;
      const float e1 = __expf(v2 - v1);  // v2 <= v1, stable
      const float s0 = 1.f / (1.f + e1);
      out[OFF_SCORES + 2 * gr] = s0;
      out[OFF_SCORES + 2 * gr + 1] = e1 * s0;
      atomicAdd(&cnt[i1], 1);
      atomicAdd(&cnt[i2], 1);
    }

    // ---- per-wave stats: butterfly over lane bits 3..5 (8 row groups) ----
    float cs[8];
#pragma unroll
    for (int q = 0; q < 8; ++q) cs[q] = p[q];
#pragma unroll
    for (int m = 8; m <= 32; m <<= 1)
#pragma unroll
      for (int q = 0; q < 8; ++q) cs[q] += __shfl_xor(cs[q], m);
    float zs = z2;
#pragma unroll
    for (int m = 8; m <= 32; m <<= 1) zs += __shfl_xor(zs, m);
    if (u < 8) {
      const float4 c0 = {cs[0], cs[1], cs[2], cs[3]};
      const float4 c1 = {cs[4], cs[5], cs[6], cs[7]};
      *(float4*)&PW[s * 64 + u * 8] = c0;
      *(float4*)&PW[s * 64 + u * 8 + 4] = c1;
      if (u == 0) zw[s] = zs;
    }
  }
  __syncthreads();

  // per-block stats -> ws (no global atomics; tiny reduce kernel finishes)
  if (t < 64) {
    const float ic =
        PW[t] + PW[64 + t] + PW[128 + t] + PW[192 + t];
    ws[(size_t)blockIdx.x * WS_STRIDE + t] = ic;
    ws[(size_t)blockIdx.x * WS_STRIDE + 64 + t] = (float)cnt[t];
  } else if (t == 64) {
    ws[(size_t)blockIdx.x * WS_STRIDE + 128] = zw[0] + zw[1] + zw[2] + zw[3];
  }
}

// ---------------------------------------------------------------------------
// Final reduction over 512 per-block stat slots; 512 threads, 4-way split.
// ---------------------------------------------------------------------------
__global__ __launch_bounds__(512) void router_reduce(
    const float* __restrict__ ws, float* __restrict__ out) {
  __shared__ float part[4][128];
  __shared__ float zp[4];
  const int t = threadIdx.x;
  const int c = t >> 7;      // block-quarter 0..3
  const int slot = t & 127;  // 0..127 (64 imp | 64 cnt)
  float v = 0.f;
#pragma unroll 8
  for (int i = 0; i < 128; ++i)
    v += ws[(size_t)(c * 128 + i) * WS_STRIDE + slot];
  part[c][slot] = v;
  if (t < 4) {
    float zz = 0.f;
#pragma unroll 8
    for (int i = 0; i < 128; ++i)
      zz += ws[(size_t)(t * 128 + i) * WS_STRIDE + 128];
    zp[t] = zz;
  }
  __syncthreads();
  if (t < 128) {
    const float s4 = part[0][t] + part[1][t] + part[2][t] + part[3][t];
    if (t < 64)
      out[OFF_IMP + t] = s4 * (1.f / 16384.f);
    else
      // counts are integers; /32768 exact; denominator max(sum,1)=32768
      out[OFF_LOAD + (t - 64)] = s4 * (1.f / 32768.f);
  } else if (t == 128) {
    out[OFF_Z] = (zp[0] + zp[1] + zp[2] + zp[3]) * (1.f / 16384.f);
  }
}

extern "C" void kernel_launch(void* const* d_in, const int* in_sizes, int n_in,
                              void* d_out, int out_size, void* d_ws, size_t ws_size,
                              hipStream_t stream) {
  const float* x = (const float*)d_in[0];
  const float* wgate = (const float*)d_in[1];
  float* out = (float*)d_out;
  float* ws = (float*)d_ws;  // 512*132 floats = 270 KB, fully written each call

  router_fused<<<dim3(NBLK), dim3(512), 0, stream>>>(x, wgate, out, ws);
  router_reduce<<<dim3(1), dim3(512), 0, stream>>>(ws, out);
}